// Round 4
// baseline (140.426 us; speedup 1.0000x reference)
//
#include <hip/hip_runtime.h>

#define NPIX (128 * 128)
#define CH 64
#define RMID 16
#define GROUPS 32
#define KK 9
#define PLANE_B (NPIX * 4)   // 65536 bytes per channel plane

// Block = 512 threads = 8 waves = 4 layers x 128 px (one full image row).
//   px    = tid & 127 : pixel within the row
//   layer = tid >> 7  : constant within each wave (wave-uniform)
// Layer L: conv1 t-rows [4L,4L+4) (no FLOP duplication), then groups [8L,8L+8).
// hq is block-uniform => row validity is uniform: interior blocks use
// compile-time immediate row offsets (-512/0/+512) in the load encoding;
// border rows (hq=0,127 -> 16 of 1024 blocks) take a generic clamped path.
// t[16] shared via LDS stride 17 (coprime with 32 banks).

template<bool INTERIOR>
__device__ __forceinline__ void run_groups(
    const char* __restrict__ xbc, char* __restrict__ obc,
    const float* __restrict__ w2, const float* __restrict__ b2,
    const float* tr, int layer, int pb,
    int cneg, int cpos, float mneg, float mpos,
    const int* roa, const float* rm)
{
#pragma unroll 2
    for (int gi = 0; gi < 8; ++gi) {
        const int g = __builtin_amdgcn_readfirstlane(layer * 8 + gi); // scalar group
        const char* c0 = xbc + (size_t)(2 * g) * PLANE_B;             // scalar bases
        const char* c1 = c0 + PLANE_B;

        // -- 18 stencil loads: s-base + per-lane col voffset + imm row offset --
        float p0[KK], p1[KK];
#pragma unroll
        for (int i = 0; i < 3; ++i) {
#pragma unroll
            for (int j = 0; j < 3; ++j) {
                const int k    = i * 3 + j;
                const int voff = (j == 0) ? cneg : (j == 2) ? cpos : pb;
                const int ro   = INTERIOR ? (i - 1) * 512 : roa[i];   // imm if interior
                p0[k] = *(const float*)(c0 + (size_t)(voff + ro));
                p1[k] = *(const float*)(c1 + (size_t)(voff + ro));
            }
        }

        // -- conv2: 9 weights from tr[16] (covers load latency) --
        float wg[KK];
#pragma unroll
        for (int k = 0; k < KK; ++k) {
            float acc = b2[g * KK + k];
            const float* w2r = w2 + (g * KK + k) * RMID;              // scalar s_load
#pragma unroll
            for (int r = 0; r < RMID; ++r)
                acc = fmaf(w2r[r], tr[r], acc);
            wg[k] = acc;
        }
        // fold border masks into weights (interior: only 6 column mults survive)
#pragma unroll
        for (int i = 0; i < 3; ++i) {
            const float rmv = INTERIOR ? 1.f : rm[i];
            wg[i * 3 + 0] *= mneg * rmv;
            wg[i * 3 + 1] *= rmv;
            wg[i * 3 + 2] *= mpos * rmv;
        }

        // -- combine + store --
        float o0 = 0.f, o1 = 0.f;
#pragma unroll
        for (int k = 0; k < KK; ++k) {
            o0 = fmaf(wg[k], p0[k], o0);
            o1 = fmaf(wg[k], p1[k], o1);
        }
        *(float*)(obc + (size_t)(2 * g) * PLANE_B + pb)       = o0;
        *(float*)(obc + (size_t)(2 * g + 1) * PLANE_B + pb)   = o1;
    }
}

__global__ __launch_bounds__(512, 6) void involution_fused(
    const float* __restrict__ x,
    const float* __restrict__ w1,
    const float* __restrict__ b1,
    const float* __restrict__ prelu_a,
    const float* __restrict__ w2,
    const float* __restrict__ b2,
    float* __restrict__ out)
{
    __shared__ float tl[128 * 17];

    const int px    = threadIdx.x & 127;
    const int layer = threadIdx.x >> 7;          // 0..3, wave-uniform

    const int blk = blockIdx.x;                  // 0..1023
    const int bq  = blk >> 7;                    // batch
    const int hq  = blk & 127;                   // row (block-uniform)
    const int p   = hq * 128 + px;

    const float* xb = x + (size_t)bq * CH * NPIX;

    // ---- Phase 1: conv1 t-rows [4*layer, 4*layer+4) ----
    const int r0 = 4 * layer;
    float t4[4];
#pragma unroll
    for (int r = 0; r < 4; ++r) t4[r] = b1[r0 + r];

#pragma unroll 16
    for (int c = 0; c < CH; ++c) {
        const float xv = xb[(size_t)c * NPIX + p];
#pragma unroll
        for (int r = 0; r < 4; ++r)
            t4[r] = fmaf(w1[(r0 + r) * CH + c], xv, t4[r]);   // w1 uniform -> s_load
    }
    const float a = prelu_a[0];
#pragma unroll
    for (int r = 0; r < 4; ++r) {
        const float v = t4[r];
        tl[px * 17 + r0 + r] = (v >= 0.f) ? v : a * v;
    }
    __syncthreads();

    // ---- Phase 2 ----
    float tr[RMID];
#pragma unroll
    for (int r = 0; r < RMID; ++r) tr[r] = tl[px * 17 + r];

    const int   pb   = 4 * p;
    const int   cneg = (px > 0)   ? pb - 4 : pb;   // clamped col voffsets
    const int   cpos = (px < 127) ? pb + 4 : pb;
    const float mneg = (px > 0)   ? 1.f : 0.f;
    const float mpos = (px < 127) ? 1.f : 0.f;

    const char* xbc = (const char*)xb;
    char*       obc = (char*)(out + (size_t)bq * CH * NPIX);

    if (hq >= 1 && hq <= 126) {
        run_groups<true>(xbc, obc, w2, b2, tr, layer, pb,
                         cneg, cpos, mneg, mpos, nullptr, nullptr);
    } else {
        int   roa[3] = { (hq > 0) ? -512 : 0, 0, (hq < 127) ? 512 : 0 };
        float rm[3]  = { (hq > 0) ? 1.f : 0.f, 1.f, (hq < 127) ? 1.f : 0.f };
        run_groups<false>(xbc, obc, w2, b2, tr, layer, pb,
                          cneg, cpos, mneg, mpos, roa, rm);
    }
}

extern "C" void kernel_launch(void* const* d_in, const int* in_sizes, int n_in,
                              void* d_out, int out_size, void* d_ws, size_t ws_size,
                              hipStream_t stream)
{
    const float* x  = (const float*)d_in[0];
    const float* w1 = (const float*)d_in[1];
    const float* b1 = (const float*)d_in[2];
    const float* pa = (const float*)d_in[3];
    const float* w2 = (const float*)d_in[4];
    const float* b2 = (const float*)d_in[5];
    float* out = (float*)d_out;

    const int nblocks = 8 * 128;   // batch * rows = 1024 blocks of 512 threads
    hipLaunchKernelGGL(involution_fused, dim3(nblocks), dim3(512), 0, stream,
                       x, w1, b1, pa, w2, b2, out);
}